// Round 7
// baseline (386.778 us; speedup 1.0000x reference)
//
#include <hip/hip_runtime.h>
#include <cstdint>

#define B_   64
#define H_   56
#define W_   56
#define C_   128
#define WSZ  7
#define TT   49
#define NN   3136            // H*W
#define MM   (B_ * NN)       // 200704
#define SCALE 0.17677669529663687f

typedef short bf16x8 __attribute__((ext_vector_type(8)));   // 8 bf16 (4 VGPRs)
typedef short bf16x4 __attribute__((ext_vector_type(4)));   // 8B (2 VGPRs)
typedef float f32x4  __attribute__((ext_vector_type(4)));
typedef unsigned short u16;

__device__ __forceinline__ float bf2f(u16 u) {
    return __uint_as_float(((unsigned int)u) << 16);
}
__device__ __forceinline__ u16 f2bf(float f) {
    unsigned int u = __float_as_uint(f);
    u += 0x7FFFu + ((u >> 16) & 1u);   // round-to-nearest-even
    return (u16)(u >> 16);
}

// ---------------------------------------------------------------------------
// KW: one-shot f32 -> bf16 weight conversion into workspace tail.
// ---------------------------------------------------------------------------
__global__ __launch_bounds__(256) void kw_cvt(
    const float* __restrict__ wqkv, const float* __restrict__ wproj,
    u16* __restrict__ wqbf, u16* __restrict__ wpbf)
{
    int g = blockIdx.x * 256 + threadIdx.x;      // 16384 float4 groups
    if (g < 12288) {                             // w_qkv: 49152 elems
        float4 f = *(const float4*)&wqkv[g * 4];
        float mul = (g < 4096) ? SCALE : 1.0f;   // q rows get SCALE folded
        ushort4 u;
        u.x = f2bf(f.x * mul); u.y = f2bf(f.y * mul);
        u.z = f2bf(f.z * mul); u.w = f2bf(f.w * mul);
        *(ushort4*)&wqbf[g * 4] = u;
    } else {                                     // w_proj: 16384 elems
        int g2 = g - 12288;
        float4 f = *(const float4*)&wproj[g2 * 4];
        ushort4 u;
        u.x = f2bf(f.x); u.y = f2bf(f.y);
        u.z = f2bf(f.z); u.w = f2bf(f.w);
        *(ushort4*)&wpbf[g2 * 4] = u;
    }
}

// ---------------------------------------------------------------------------
// KA v5: fused qkv-GEMM + windowed attention (structure proven at 147 us).
// YBF=true: attention output stored as bf16 to ybf (51.4 MB instead of
// 102.8 MB f32) -- halves ka's write and kb's read. One extra bf16 rounding
// of y before the (already existing) z rounding.
// ---------------------------------------------------------------------------
template <bool PREW, bool YBF>
__global__ __launch_bounds__(256, 3) void ka_fused(
    const float* __restrict__ x, const float* __restrict__ wqkv,
    const u16* __restrict__ wqbf,
    u16* __restrict__ vout, u16* __restrict__ ybf, float* __restrict__ out)
{
    __shared__ u16 lds[26240];                       // 52,480 B
    u16 (*xq)[136] = (u16(*)[136])&lds[0];           // x, later q
    u16 (*ks)[136] = (u16(*)[136])&lds[8704];        // k
    u16 (*vs)[138] = (u16(*)[138])&lds[17408];       // v
    u16* ps_ = &lds[0];                              // P: 256 x 68 u16 overlay

    const int t   = threadIdx.x;
    const int blk = blockIdx.x;
    const int b_  = blk >> 6, wr = blk & 63;
    const int qy  = wr >> 3, qx = wr & 7;
    const int wave = t >> 6, lane = t & 63, lr = lane & 15, quad = lane >> 4;

    // ---- phase 0: stage x window -> xq (bf16), zero pad rows ----
    for (int i = t; i < 64 * 32; i += 256) {
        int tok = i >> 5, c4 = (i & 31) * 4;
        ushort4 u4 = {0, 0, 0, 0};
        if (tok < TT) {
            int hh = qy * WSZ + tok / WSZ, ww = qx * WSZ + tok % WSZ;
            float4 f = *(const float4*)&x[((size_t)b_ * NN + hh * W_ + ww) * C_ + c4];
            u4.x = f2bf(f.x); u4.y = f2bf(f.y);
            u4.z = f2bf(f.z); u4.w = f2bf(f.w);
        }
        *(ushort4*)&xq[tok][c4] = u4;
    }
    __syncthreads();

    // ---- phase 1a: k (ch=1) -> ks, v (ch=2) -> vs + global. ----
#pragma unroll
    for (int cc = 0; cc < 2; cc++) {
        const int ch = 1 + cc;
        u16* dstbase = cc ? &vs[0][0] : &ks[0][0];
        const int dstride = cc ? 138 : 136;
#pragma unroll
        for (int half = 0; half < 2; half++) {
            const int wrowi = ch * 128 + half * 64 + wave * 16 + lr;
            const float* wrowf = &wqkv[(size_t)wrowi * C_];
            const u16*   wrowb = &wqbf[(size_t)wrowi * C_];
            f32x4 acc[4];
#pragma unroll
            for (int mi = 0; mi < 4; mi++) acc[mi] = {0.f, 0.f, 0.f, 0.f};
#pragma unroll
            for (int kk = 0; kk < 4; kk++) {
                bf16x8 bfr;
                if constexpr (PREW) {
                    bfr = *(const bf16x8*)&wrowb[kk * 32 + quad * 8];
                } else {
                    float4 f0 = *(const float4*)&wrowf[kk * 32 + quad * 8];
                    float4 f1 = *(const float4*)&wrowf[kk * 32 + quad * 8 + 4];
                    bfr[0] = (short)f2bf(f0.x); bfr[1] = (short)f2bf(f0.y);
                    bfr[2] = (short)f2bf(f0.z); bfr[3] = (short)f2bf(f0.w);
                    bfr[4] = (short)f2bf(f1.x); bfr[5] = (short)f2bf(f1.y);
                    bfr[6] = (short)f2bf(f1.z); bfr[7] = (short)f2bf(f1.w);
                }
#pragma unroll
                for (int mi = 0; mi < 4; mi++) {
                    bf16x8 afr = *(const bf16x8*)&xq[mi * 16 + lr][kk * 32 + quad * 8];
                    acc[mi] = __builtin_amdgcn_mfma_f32_16x16x32_bf16(
                        afr, bfr, acc[mi], 0, 0, 0);
                }
            }
#pragma unroll
            for (int mi = 0; mi < 4; mi++) {
#pragma unroll
                for (int r = 0; r < 4; r++) {
                    int tok = mi * 16 + quad * 4 + r;
                    int col = half * 64 + wave * 16 + lr;
                    u16 bv = f2bf(acc[mi][r]);
                    dstbase[tok * dstride + col] = bv;
                    if (cc == 1 && tok < TT) {
                        int hh2 = qy * WSZ + tok / WSZ;
                        int ww2 = qx * WSZ + tok % WSZ;
                        vout[((size_t)b_ * NN + hh2 * W_ + ww2) * C_ + col] = bv;
                    }
                }
            }
        }
    }

    // ---- phase 1b: q accumulators in registers (x still live) ----
    const float qmul = PREW ? 1.0f : SCALE;      // SCALE folded into wqbf
    f32x4 qacc[2][4];
#pragma unroll
    for (int half = 0; half < 2; half++)
#pragma unroll
        for (int mi = 0; mi < 4; mi++) qacc[half][mi] = {0.f, 0.f, 0.f, 0.f};
#pragma unroll
    for (int half = 0; half < 2; half++) {
        const int wrowi = half * 64 + wave * 16 + lr;
        const float* wrowf = &wqkv[(size_t)wrowi * C_];
        const u16*   wrowb = &wqbf[(size_t)wrowi * C_];
#pragma unroll
        for (int kk = 0; kk < 4; kk++) {
            bf16x8 bfr;
            if constexpr (PREW) {
                bfr = *(const bf16x8*)&wrowb[kk * 32 + quad * 8];
            } else {
                float4 f0 = *(const float4*)&wrowf[kk * 32 + quad * 8];
                float4 f1 = *(const float4*)&wrowf[kk * 32 + quad * 8 + 4];
                bfr[0] = (short)f2bf(f0.x); bfr[1] = (short)f2bf(f0.y);
                bfr[2] = (short)f2bf(f0.z); bfr[3] = (short)f2bf(f0.w);
                bfr[4] = (short)f2bf(f1.x); bfr[5] = (short)f2bf(f1.y);
                bfr[6] = (short)f2bf(f1.z); bfr[7] = (short)f2bf(f1.w);
            }
#pragma unroll
            for (int mi = 0; mi < 4; mi++) {
                bf16x8 afr = *(const bf16x8*)&xq[mi * 16 + lr][kk * 32 + quad * 8];
                qacc[half][mi] = __builtin_amdgcn_mfma_f32_16x16x32_bf16(
                    afr, bfr, qacc[half][mi], 0, 0, 0);
            }
        }
    }
    __syncthreads();   // all x reads done; k/v published

    // write q (scaled) over the x slab
#pragma unroll
    for (int half = 0; half < 2; half++)
#pragma unroll
        for (int mi = 0; mi < 4; mi++)
#pragma unroll
            for (int r = 0; r < 4; r++)
                xq[mi * 16 + quad * 4 + r][half * 64 + wave * 16 + lr] =
                    f2bf(qacc[half][mi][r] * qmul);
    __syncthreads();   // q published

    // ---- phase 2: attention, wave = head ----
    const int h = wave;
    bf16x8 qf[4], kf[4];
#pragma unroll
    for (int mi = 0; mi < 4; mi++) {
        qf[mi] = *(const bf16x8*)&xq[mi * 16 + lr][h * 32 + quad * 8];
        kf[mi] = *(const bf16x8*)&ks[mi * 16 + lr][h * 32 + quad * 8];
    }
    __syncthreads();   // all waves hold q/k frags -> ps overlay now safe

    f32x4 s[4][4];
#pragma unroll
    for (int mi = 0; mi < 4; mi++)
#pragma unroll
        for (int nj = 0; nj < 4; nj++) s[mi][nj] = {0.f, 0.f, 0.f, 0.f};
#pragma unroll
    for (int mi = 0; mi < 4; mi++)
#pragma unroll
        for (int nj = 0; nj < 4; nj++)
            s[mi][nj] = __builtin_amdgcn_mfma_f32_16x16x32_bf16(
                qf[mi], kf[nj], s[mi][nj], 0, 0, 0);

    // mask pad key columns j = 48 + lr, lr >= 1
    if (lr >= 1) {
#pragma unroll
        for (int mi = 0; mi < 4; mi++)
#pragma unroll
            for (int r = 0; r < 4; r++) s[mi][3][r] = -1e30f;
    }

    float rsum[4][4];
#pragma unroll
    for (int mi = 0; mi < 4; mi++) {
#pragma unroll
        for (int r = 0; r < 4; r++) {
            float mx = fmaxf(fmaxf(s[mi][0][r], s[mi][1][r]),
                             fmaxf(s[mi][2][r], s[mi][3][r]));
#pragma unroll
            for (int off = 1; off < 16; off <<= 1)
                mx = fmaxf(mx, __shfl_xor(mx, off));
            float sum = 0.f;
#pragma unroll
            for (int nj = 0; nj < 4; nj++) {
                float p = __expf(s[mi][nj][r] - mx);
                s[mi][nj][r] = p;
                sum += p;
            }
#pragma unroll
            for (int off = 1; off < 16; off <<= 1)
                sum += __shfl_xor(sum, off);
            rsum[mi][r] = sum;
        }
    }

    // P: C-layout -> LDS (overlay, stride 68 = conflict-free) -> A-layout
#pragma unroll
    for (int mi = 0; mi < 4; mi++)
#pragma unroll
        for (int nj = 0; nj < 4; nj++)
#pragma unroll
            for (int r = 0; r < 4; r++)
                ps_[((h * 64) + mi * 16 + quad * 4 + r) * 68 + nj * 16 + lr] =
                    f2bf(s[mi][nj][r]);

    f32x4 o[4][2];
#pragma unroll
    for (int mi = 0; mi < 4; mi++)
#pragma unroll
        for (int nv = 0; nv < 2; nv++) o[mi][nv] = {0.f, 0.f, 0.f, 0.f};

#pragma unroll
    for (int kt = 0; kt < 2; kt++) {
        bf16x8 pf[4];
#pragma unroll
        for (int mi = 0; mi < 4; mi++) {
            const u16* pp = &ps_[((h * 64) + mi * 16 + lr) * 68 + kt * 32 + quad * 8];
            bf16x4 lo = *(const bf16x4*)&pp[0];    // 8B-aligned (rows stride 136B)
            bf16x4 hi = *(const bf16x4*)&pp[4];
            bf16x8 f;
            f[0] = lo[0]; f[1] = lo[1]; f[2] = lo[2]; f[3] = lo[3];
            f[4] = hi[0]; f[5] = hi[1]; f[6] = hi[2]; f[7] = hi[3];
            pf[mi] = f;
        }
        bf16x8 vf[2];
#pragma unroll
        for (int nv = 0; nv < 2; nv++) {
            bf16x8 tmp;
#pragma unroll
            for (int jj = 0; jj < 8; jj++)
                tmp[jj] = (short)vs[kt * 32 + quad * 8 + jj][h * 32 + nv * 16 + lr];
            vf[nv] = tmp;
        }
#pragma unroll
        for (int mi = 0; mi < 4; mi++)
#pragma unroll
            for (int nv = 0; nv < 2; nv++)
                o[mi][nv] = __builtin_amdgcn_mfma_f32_16x16x32_bf16(
                    pf[mi], vf[nv], o[mi][nv], 0, 0, 0);
    }

#pragma unroll
    for (int mi = 0; mi < 4; mi++) {
#pragma unroll
        for (int r = 0; r < 4; r++) {
            int i = mi * 16 + quad * 4 + r;
            if (i < TT) {
                int hh = qy * WSZ + i / WSZ, ww = qx * WSZ + i % WSZ;
                size_t orow = (size_t)b_ * NN + hh * W_ + ww;
                float inv = 1.f / rsum[mi][r];
#pragma unroll
                for (int nv = 0; nv < 2; nv++) {
                    float val = o[mi][nv][r] * inv;
                    if constexpr (YBF)
                        ybf[orow * C_ + h * 32 + nv * 16 + lr] = f2bf(val);
                    else
                        out[orow * C_ + h * 32 + nv * 16 + lr] = val;
                }
            }
        }
    }
}

// ---------------------------------------------------------------------------
// KB v4: depthwise 3x3 conv on bf16 v (IMAGE layout B,H,W,C), one thread =
// 8 channels of one position, high occupancy.
// INPLACE=true: z = bf16(bf2f(ybf) + bias + conv) written back IN PLACE over
// ybf (each thread RMWs only its own 16 B -> race-free). No extra workspace.
// INPLACE=false: legacy f32 RMW into out (proven fallback).
// ---------------------------------------------------------------------------
template <bool INPLACE>
__global__ __launch_bounds__(256) void kb_lim(
    const u16* __restrict__ v, const float* __restrict__ wlim,
    const float* __restrict__ blim, u16* __restrict__ z,
    float* __restrict__ out)
{
    const int t   = threadIdx.x;
    const int pos = blockIdx.x * 16 + (t >> 4);
    const int c0  = (t & 15) * 8;
    const int b_  = pos / NN;
    const int rem = pos - b_ * NN;
    const int hh  = rem / W_;
    const int ww  = rem - hh * W_;

    // issue the y / out load early (hides under weight loads + taps)
    bf16x8 yv;
    float4 o0, o1;
    if constexpr (INPLACE) {
        yv = *(const bf16x8*)&z[(size_t)pos * C_ + c0];
    } else {
        o0 = *(const float4*)&out[(size_t)pos * C_ + c0];
        o1 = *(const float4*)&out[(size_t)pos * C_ + c0 + 4];
    }

    float w72[72];
    {
        const float* wp = &wlim[c0 * 9];
#pragma unroll
        for (int i = 0; i < 18; i++) {
            float4 f = *(const float4*)&wp[i * 4];
            w72[i * 4 + 0] = f.x; w72[i * 4 + 1] = f.y;
            w72[i * 4 + 2] = f.z; w72[i * 4 + 3] = f.w;
        }
    }
    float acc[8];
    {
        float4 b0 = *(const float4*)&blim[c0];
        float4 b1 = *(const float4*)&blim[c0 + 4];
        acc[0] = b0.x; acc[1] = b0.y; acc[2] = b0.z; acc[3] = b0.w;
        acc[4] = b1.x; acc[5] = b1.y; acc[6] = b1.z; acc[7] = b1.w;
    }

    const u16* vbase = &v[(size_t)b_ * NN * C_ + c0];
#pragma unroll
    for (int dy = -1; dy <= 1; dy++) {
        int yy = hh + dy;
        bool yok = (unsigned)yy < (unsigned)H_;
#pragma unroll
        for (int dx = -1; dx <= 1; dx++) {
            int x2 = ww + dx;
            bool ok = yok && ((unsigned)x2 < (unsigned)W_);
            bf16x8 vv = {0, 0, 0, 0, 0, 0, 0, 0};
            if (ok) vv = *(const bf16x8*)&vbase[(size_t)(yy * W_ + x2) * C_];
            const int tap = (dy + 1) * 3 + (dx + 1);
#pragma unroll
            for (int j = 0; j < 8; j++)
                acc[j] += bf2f((u16)vv[j]) * w72[j * 9 + tap];
        }
    }

    if constexpr (INPLACE) {
        bf16x8 zz;
#pragma unroll
        for (int j = 0; j < 8; j++)
            zz[j] = (short)f2bf(bf2f((u16)yv[j]) + acc[j]);
        *(bf16x8*)&z[(size_t)pos * C_ + c0] = zz;
    } else {
        o0.x += acc[0]; o0.y += acc[1]; o0.z += acc[2]; o0.w += acc[3];
        o1.x += acc[4]; o1.y += acc[5]; o1.z += acc[6]; o1.w += acc[7];
        *(float4*)&out[(size_t)pos * C_ + c0]     = o0;
        *(float4*)&out[(size_t)pos * C_ + c0 + 4] = o1;
    }
}

// ---------------------------------------------------------------------------
// KC v4 (direct): out = z @ w_proj^T + b_proj -- NO LDS, NO barriers.
// Each lane loads its MFMA fragments straight from global: A from bf16 z
// (16-B loads; each 256-B z row fully consumed across kk/kt via L1),
// B from the 32 KB L2-resident wpbf. Waves fully independent -> pure
// streaming; replaces the barrier-lockstep staged version (~140 us) whose
// K=128 made every block a short serial latency chain.
// ---------------------------------------------------------------------------
__global__ __launch_bounds__(256, 4) void kc_direct(
    const u16* __restrict__ z, const u16* __restrict__ wpbf,
    const float* __restrict__ bproj, float* __restrict__ out)
{
    const int t    = threadIdx.x;
    const int m0   = blockIdx.x * 128;
    const int wave = t >> 6, lane = t & 63, lr = lane & 15, quad = lane >> 4;
    const int wm = (wave >> 1) * 64, wn = (wave & 1) * 64;

    f32x4 acc[4][4];
#pragma unroll
    for (int mi = 0; mi < 4; mi++)
#pragma unroll
        for (int ni = 0; ni < 4; ni++) acc[mi][ni] = {0.f, 0.f, 0.f, 0.f};

#pragma unroll
    for (int kt = 0; kt < 2; kt++) {
#pragma unroll
        for (int kk = 0; kk < 2; kk++) {
            const int kcol = kt * 64 + kk * 32 + quad * 8;
            bf16x8 a[4], b[4];
#pragma unroll
            for (int mi = 0; mi < 4; mi++)
                a[mi] = *(const bf16x8*)&z[(size_t)(m0 + wm + mi * 16 + lr) * C_ + kcol];
#pragma unroll
            for (int ni = 0; ni < 4; ni++)
                b[ni] = *(const bf16x8*)&wpbf[(size_t)(wn + ni * 16 + lr) * C_ + kcol];
#pragma unroll
            for (int mi = 0; mi < 4; mi++)
#pragma unroll
                for (int ni = 0; ni < 4; ni++)
                    acc[mi][ni] = __builtin_amdgcn_mfma_f32_16x16x32_bf16(
                        a[mi], b[ni], acc[mi][ni], 0, 0, 0);
        }
    }

#pragma unroll
    for (int mi = 0; mi < 4; mi++) {
#pragma unroll
        for (int r = 0; r < 4; r++) {
            int m = m0 + wm + mi * 16 + quad * 4 + r;
#pragma unroll
            for (int ni = 0; ni < 4; ni++) {
                int c = wn + ni * 16 + lr;
                out[(size_t)m * C_ + c] = acc[mi][ni][r] + bproj[c];
            }
        }
    }
}

// ---------------------------------------------------------------------------
// KC legacy (fallback paths): staged gemm_bt. MODE 1: A from f32 y + f2bf,
// W from wpbf. MODE 0: full f32.
// ---------------------------------------------------------------------------
template <int MODE>
__global__ __launch_bounds__(256) void kc_proj(
    float* __restrict__ y, const float* __restrict__ wproj,
    const u16* __restrict__ wpbf, const float* __restrict__ bproj)
{
    __shared__ u16 As[128][72];
    __shared__ u16 Ws[128][72];
    const int t    = threadIdx.x;
    const int m0   = blockIdx.x * 128;
    const int wave = t >> 6, lane = t & 63, lr = lane & 15, quad = lane >> 4;
    const int wm = (wave >> 1) * 64, wn = (wave & 1) * 64;

    f32x4 acc[4][4];
#pragma unroll
    for (int mi = 0; mi < 4; mi++)
#pragma unroll
        for (int ni = 0; ni < 4; ni++) acc[mi][ni] = {0.f, 0.f, 0.f, 0.f};

#pragma unroll
    for (int kt = 0; kt < 2; kt++) {
        const int k0 = kt * 64;
#pragma unroll
        for (int p = 0; p < 8; p++) {
            int e   = p * 256 + t;
            int row = e >> 4;
            int col = (e & 15) * 4;
            float4 fa = *(const float4*)&y[(size_t)(m0 + row) * C_ + k0 + col];
            ushort4 ua;
            ua.x = f2bf(fa.x); ua.y = f2bf(fa.y);
            ua.z = f2bf(fa.z); ua.w = f2bf(fa.w);
            *(ushort4*)&As[row][col] = ua;
            if constexpr (MODE == 0) {
                float4 fw = *(const float4*)&wproj[(size_t)row * C_ + k0 + col];
                ushort4 uw;
                uw.x = f2bf(fw.x); uw.y = f2bf(fw.y);
                uw.z = f2bf(fw.z); uw.w = f2bf(fw.w);
                *(ushort4*)&Ws[row][col] = uw;
            }
        }
        if constexpr (MODE >= 1) {
#pragma unroll
            for (int p4 = 0; p4 < 4; p4++) {
                int e    = p4 * 256 + t;
                int row  = e >> 3;
                int col8 = (e & 7) * 8;
                *(bf16x8*)&Ws[row][col8] =
                    *(const bf16x8*)&wpbf[(size_t)row * C_ + k0 + col8];
            }
        }
        __syncthreads();
#pragma unroll
        for (int kk = 0; kk < 2; kk++) {
            bf16x8 a[4], b[4];
#pragma unroll
            for (int mi = 0; mi < 4; mi++)
                a[mi] = *(const bf16x8*)&As[wm + mi * 16 + lr][kk * 32 + quad * 8];
#pragma unroll
            for (int ni = 0; ni < 4; ni++)
                b[ni] = *(const bf16x8*)&Ws[wn + ni * 16 + lr][kk * 32 + quad * 8];
#pragma unroll
            for (int mi = 0; mi < 4; mi++)
#pragma unroll
                for (int ni = 0; ni < 4; ni++)
                    acc[mi][ni] = __builtin_amdgcn_mfma_f32_16x16x32_bf16(
                        a[mi], b[ni], acc[mi][ni], 0, 0, 0);
        }
        if (kt == 0) __syncthreads();
    }

#pragma unroll
    for (int mi = 0; mi < 4; mi++) {
#pragma unroll
        for (int r = 0; r < 4; r++) {
            int m = m0 + wm + mi * 16 + quad * 4 + r;
#pragma unroll
            for (int ni = 0; ni < 4; ni++) {
                int c = wn + ni * 16 + lr;
                y[(size_t)m * C_ + c] = acc[mi][ni][r] + bproj[c];
            }
        }
    }
}

extern "C" void kernel_launch(void* const* d_in, const int* in_sizes, int n_in,
                              void* d_out, int out_size, void* d_ws, size_t ws_size,
                              hipStream_t stream)
{
    const float* x     = (const float*)d_in[0];
    const float* wqkv  = (const float*)d_in[1];
    const float* wlim  = (const float*)d_in[2];
    const float* blim  = (const float*)d_in[3];
    const float* wproj = (const float*)d_in[4];
    const float* bproj = (const float*)d_in[5];
    float* out = (float*)d_out;
    u16*   v   = (u16*)d_ws;                         // 51,380,224 B bf16 image v

    const size_t vbytes = (size_t)MM * C_ * 2;       // 51,380,224 (256B-aligned)
    const size_t wbytes = (49152 + 16384) * 2;       // 131,072
    const size_t need1  = vbytes + wbytes;           // weights path
    const size_t need2  = need1 + vbytes;            // + bf16 ybf/z buffer

    if (ws_size >= need2) {
        u16* wqbf = (u16*)((char*)d_ws + vbytes);
        u16* wpbf = wqbf + 49152;
        u16* zbuf = (u16*)((char*)d_ws + need1);     // ybf, then z in place
        kw_cvt<<<dim3(64), 256, 0, stream>>>(wqkv, wproj, wqbf, wpbf);
        ka_fused<true, true><<<dim3(B_ * 64), 256, 0, stream>>>(
            x, wqkv, wqbf, v, zbuf, nullptr);
        kb_lim<true><<<dim3(MM / 16), 256, 0, stream>>>(v, wlim, blim, zbuf, nullptr);
        kc_direct<<<dim3(MM / 128), 256, 0, stream>>>(zbuf, wpbf, bproj, out);
    } else if (ws_size >= need1) {
        u16* wqbf = (u16*)((char*)d_ws + vbytes);
        u16* wpbf = wqbf + 49152;
        kw_cvt<<<dim3(64), 256, 0, stream>>>(wqkv, wproj, wqbf, wpbf);
        ka_fused<true, false><<<dim3(B_ * 64), 256, 0, stream>>>(
            x, wqkv, wqbf, v, nullptr, out);
        kb_lim<false><<<dim3(MM / 16), 256, 0, stream>>>(v, wlim, blim, nullptr, out);
        kc_proj<1><<<dim3(MM / 128), 256, 0, stream>>>(out, nullptr, wpbf, bproj);
    } else {
        ka_fused<false, false><<<dim3(B_ * 64), 256, 0, stream>>>(
            x, wqkv, nullptr, v, nullptr, out);
        kb_lim<false><<<dim3(MM / 16), 256, 0, stream>>>(v, wlim, blim, nullptr, out);
        kc_proj<0><<<dim3(MM / 128), 256, 0, stream>>>(out, wproj, nullptr, bproj);
    }
}

// Round 8
// 380.720 us; speedup vs baseline: 1.0159x; 1.0159x over previous
//
#include <hip/hip_runtime.h>
#include <cstdint>

#define B_   64
#define H_   56
#define W_   56
#define C_   128
#define WSZ  7
#define TT   49
#define NN   3136            // H*W
#define MM   (B_ * NN)       // 200704
#define SCALE 0.17677669529663687f

typedef short bf16x8 __attribute__((ext_vector_type(8)));   // 8 bf16 (4 VGPRs)
typedef short bf16x4 __attribute__((ext_vector_type(4)));   // 8B (2 VGPRs)
typedef float f32x4  __attribute__((ext_vector_type(4)));
typedef unsigned short u16;

__device__ __forceinline__ float bf2f(u16 u) {
    return __uint_as_float(((unsigned int)u) << 16);
}
__device__ __forceinline__ u16 f2bf(float f) {
    unsigned int u = __float_as_uint(f);
    u += 0x7FFFu + ((u >> 16) & 1u);   // round-to-nearest-even
    return (u16)(u >> 16);
}

// ---------------------------------------------------------------------------
// KW: one-shot f32 -> bf16 weight conversion into workspace tail.
// ---------------------------------------------------------------------------
__global__ __launch_bounds__(256) void kw_cvt(
    const float* __restrict__ wqkv, const float* __restrict__ wproj,
    u16* __restrict__ wqbf, u16* __restrict__ wpbf)
{
    int g = blockIdx.x * 256 + threadIdx.x;      // 16384 float4 groups
    if (g < 12288) {                             // w_qkv: 49152 elems
        float4 f = *(const float4*)&wqkv[g * 4];
        float mul = (g < 4096) ? SCALE : 1.0f;   // q rows get SCALE folded
        ushort4 u;
        u.x = f2bf(f.x * mul); u.y = f2bf(f.y * mul);
        u.z = f2bf(f.z * mul); u.w = f2bf(f.w * mul);
        *(ushort4*)&wqbf[g * 4] = u;
    } else {                                     // w_proj: 16384 elems
        int g2 = g - 12288;
        float4 f = *(const float4*)&wproj[g2 * 4];
        ushort4 u;
        u.x = f2bf(f.x); u.y = f2bf(f.y);
        u.z = f2bf(f.z); u.w = f2bf(f.w);
        *(ushort4*)&wpbf[g2 * 4] = u;
    }
}

// ---------------------------------------------------------------------------
// KA v5 (unchanged from round 7 -- proven at 140 us): fused qkv-GEMM +
// windowed attention. YBF=true stores attention output as bf16 (halves write).
// ---------------------------------------------------------------------------
template <bool PREW, bool YBF>
__global__ __launch_bounds__(256, 3) void ka_fused(
    const float* __restrict__ x, const float* __restrict__ wqkv,
    const u16* __restrict__ wqbf,
    u16* __restrict__ vout, u16* __restrict__ ybf, float* __restrict__ out)
{
    __shared__ u16 lds[26240];                       // 52,480 B
    u16 (*xq)[136] = (u16(*)[136])&lds[0];           // x, later q
    u16 (*ks)[136] = (u16(*)[136])&lds[8704];        // k
    u16 (*vs)[138] = (u16(*)[138])&lds[17408];       // v
    u16* ps_ = &lds[0];                              // P: 256 x 68 u16 overlay

    const int t   = threadIdx.x;
    const int blk = blockIdx.x;
    const int b_  = blk >> 6, wr = blk & 63;
    const int qy  = wr >> 3, qx = wr & 7;
    const int wave = t >> 6, lane = t & 63, lr = lane & 15, quad = lane >> 4;

    // ---- phase 0: stage x window -> xq (bf16), zero pad rows ----
    for (int i = t; i < 64 * 32; i += 256) {
        int tok = i >> 5, c4 = (i & 31) * 4;
        ushort4 u4 = {0, 0, 0, 0};
        if (tok < TT) {
            int hh = qy * WSZ + tok / WSZ, ww = qx * WSZ + tok % WSZ;
            float4 f = *(const float4*)&x[((size_t)b_ * NN + hh * W_ + ww) * C_ + c4];
            u4.x = f2bf(f.x); u4.y = f2bf(f.y);
            u4.z = f2bf(f.z); u4.w = f2bf(f.w);
        }
        *(ushort4*)&xq[tok][c4] = u4;
    }
    __syncthreads();

    // ---- phase 1a: k (ch=1) -> ks, v (ch=2) -> vs + global. ----
#pragma unroll
    for (int cc = 0; cc < 2; cc++) {
        const int ch = 1 + cc;
        u16* dstbase = cc ? &vs[0][0] : &ks[0][0];
        const int dstride = cc ? 138 : 136;
#pragma unroll
        for (int half = 0; half < 2; half++) {
            const int wrowi = ch * 128 + half * 64 + wave * 16 + lr;
            const float* wrowf = &wqkv[(size_t)wrowi * C_];
            const u16*   wrowb = &wqbf[(size_t)wrowi * C_];
            f32x4 acc[4];
#pragma unroll
            for (int mi = 0; mi < 4; mi++) acc[mi] = {0.f, 0.f, 0.f, 0.f};
#pragma unroll
            for (int kk = 0; kk < 4; kk++) {
                bf16x8 bfr;
                if constexpr (PREW) {
                    bfr = *(const bf16x8*)&wrowb[kk * 32 + quad * 8];
                } else {
                    float4 f0 = *(const float4*)&wrowf[kk * 32 + quad * 8];
                    float4 f1 = *(const float4*)&wrowf[kk * 32 + quad * 8 + 4];
                    bfr[0] = (short)f2bf(f0.x); bfr[1] = (short)f2bf(f0.y);
                    bfr[2] = (short)f2bf(f0.z); bfr[3] = (short)f2bf(f0.w);
                    bfr[4] = (short)f2bf(f1.x); bfr[5] = (short)f2bf(f1.y);
                    bfr[6] = (short)f2bf(f1.z); bfr[7] = (short)f2bf(f1.w);
                }
#pragma unroll
                for (int mi = 0; mi < 4; mi++) {
                    bf16x8 afr = *(const bf16x8*)&xq[mi * 16 + lr][kk * 32 + quad * 8];
                    acc[mi] = __builtin_amdgcn_mfma_f32_16x16x32_bf16(
                        afr, bfr, acc[mi], 0, 0, 0);
                }
            }
#pragma unroll
            for (int mi = 0; mi < 4; mi++) {
#pragma unroll
                for (int r = 0; r < 4; r++) {
                    int tok = mi * 16 + quad * 4 + r;
                    int col = half * 64 + wave * 16 + lr;
                    u16 bv = f2bf(acc[mi][r]);
                    dstbase[tok * dstride + col] = bv;
                    if (cc == 1 && tok < TT) {
                        int hh2 = qy * WSZ + tok / WSZ;
                        int ww2 = qx * WSZ + tok % WSZ;
                        vout[((size_t)b_ * NN + hh2 * W_ + ww2) * C_ + col] = bv;
                    }
                }
            }
        }
    }

    // ---- phase 1b: q accumulators in registers (x still live) ----
    const float qmul = PREW ? 1.0f : SCALE;      // SCALE folded into wqbf
    f32x4 qacc[2][4];
#pragma unroll
    for (int half = 0; half < 2; half++)
#pragma unroll
        for (int mi = 0; mi < 4; mi++) qacc[half][mi] = {0.f, 0.f, 0.f, 0.f};
#pragma unroll
    for (int half = 0; half < 2; half++) {
        const int wrowi = half * 64 + wave * 16 + lr;
        const float* wrowf = &wqkv[(size_t)wrowi * C_];
        const u16*   wrowb = &wqbf[(size_t)wrowi * C_];
#pragma unroll
        for (int kk = 0; kk < 4; kk++) {
            bf16x8 bfr;
            if constexpr (PREW) {
                bfr = *(const bf16x8*)&wrowb[kk * 32 + quad * 8];
            } else {
                float4 f0 = *(const float4*)&wrowf[kk * 32 + quad * 8];
                float4 f1 = *(const float4*)&wrowf[kk * 32 + quad * 8 + 4];
                bfr[0] = (short)f2bf(f0.x); bfr[1] = (short)f2bf(f0.y);
                bfr[2] = (short)f2bf(f0.z); bfr[3] = (short)f2bf(f0.w);
                bfr[4] = (short)f2bf(f1.x); bfr[5] = (short)f2bf(f1.y);
                bfr[6] = (short)f2bf(f1.z); bfr[7] = (short)f2bf(f1.w);
            }
#pragma unroll
            for (int mi = 0; mi < 4; mi++) {
                bf16x8 afr = *(const bf16x8*)&xq[mi * 16 + lr][kk * 32 + quad * 8];
                qacc[half][mi] = __builtin_amdgcn_mfma_f32_16x16x32_bf16(
                    afr, bfr, qacc[half][mi], 0, 0, 0);
            }
        }
    }
    __syncthreads();   // all x reads done; k/v published

    // write q (scaled) over the x slab
#pragma unroll
    for (int half = 0; half < 2; half++)
#pragma unroll
        for (int mi = 0; mi < 4; mi++)
#pragma unroll
            for (int r = 0; r < 4; r++)
                xq[mi * 16 + quad * 4 + r][half * 64 + wave * 16 + lr] =
                    f2bf(qacc[half][mi][r] * qmul);
    __syncthreads();   // q published

    // ---- phase 2: attention, wave = head ----
    const int h = wave;
    bf16x8 qf[4], kf[4];
#pragma unroll
    for (int mi = 0; mi < 4; mi++) {
        qf[mi] = *(const bf16x8*)&xq[mi * 16 + lr][h * 32 + quad * 8];
        kf[mi] = *(const bf16x8*)&ks[mi * 16 + lr][h * 32 + quad * 8];
    }
    __syncthreads();   // all waves hold q/k frags -> ps overlay now safe

    f32x4 s[4][4];
#pragma unroll
    for (int mi = 0; mi < 4; mi++)
#pragma unroll
        for (int nj = 0; nj < 4; nj++) s[mi][nj] = {0.f, 0.f, 0.f, 0.f};
#pragma unroll
    for (int mi = 0; mi < 4; mi++)
#pragma unroll
        for (int nj = 0; nj < 4; nj++)
            s[mi][nj] = __builtin_amdgcn_mfma_f32_16x16x32_bf16(
                qf[mi], kf[nj], s[mi][nj], 0, 0, 0);

    // mask pad key columns j = 48 + lr, lr >= 1
    if (lr >= 1) {
#pragma unroll
        for (int mi = 0; mi < 4; mi++)
#pragma unroll
            for (int r = 0; r < 4; r++) s[mi][3][r] = -1e30f;
    }

    float rsum[4][4];
#pragma unroll
    for (int mi = 0; mi < 4; mi++) {
#pragma unroll
        for (int r = 0; r < 4; r++) {
            float mx = fmaxf(fmaxf(s[mi][0][r], s[mi][1][r]),
                             fmaxf(s[mi][2][r], s[mi][3][r]));
#pragma unroll
            for (int off = 1; off < 16; off <<= 1)
                mx = fmaxf(mx, __shfl_xor(mx, off));
            float sum = 0.f;
#pragma unroll
            for (int nj = 0; nj < 4; nj++) {
                float p = __expf(s[mi][nj][r] - mx);
                s[mi][nj][r] = p;
                sum += p;
            }
#pragma unroll
            for (int off = 1; off < 16; off <<= 1)
                sum += __shfl_xor(sum, off);
            rsum[mi][r] = sum;
        }
    }

    // P: C-layout -> LDS (overlay, stride 68 = conflict-free) -> A-layout
#pragma unroll
    for (int mi = 0; mi < 4; mi++)
#pragma unroll
        for (int nj = 0; nj < 4; nj++)
#pragma unroll
            for (int r = 0; r < 4; r++)
                ps_[((h * 64) + mi * 16 + quad * 4 + r) * 68 + nj * 16 + lr] =
                    f2bf(s[mi][nj][r]);

    f32x4 o[4][2];
#pragma unroll
    for (int mi = 0; mi < 4; mi++)
#pragma unroll
        for (int nv = 0; nv < 2; nv++) o[mi][nv] = {0.f, 0.f, 0.f, 0.f};

#pragma unroll
    for (int kt = 0; kt < 2; kt++) {
        bf16x8 pf[4];
#pragma unroll
        for (int mi = 0; mi < 4; mi++) {
            const u16* pp = &ps_[((h * 64) + mi * 16 + lr) * 68 + kt * 32 + quad * 8];
            bf16x4 lo = *(const bf16x4*)&pp[0];    // 8B-aligned (rows stride 136B)
            bf16x4 hi = *(const bf16x4*)&pp[4];
            bf16x8 f;
            f[0] = lo[0]; f[1] = lo[1]; f[2] = lo[2]; f[3] = lo[3];
            f[4] = hi[0]; f[5] = hi[1]; f[6] = hi[2]; f[7] = hi[3];
            pf[mi] = f;
        }
        bf16x8 vf[2];
#pragma unroll
        for (int nv = 0; nv < 2; nv++) {
            bf16x8 tmp;
#pragma unroll
            for (int jj = 0; jj < 8; jj++)
                tmp[jj] = (short)vs[kt * 32 + quad * 8 + jj][h * 32 + nv * 16 + lr];
            vf[nv] = tmp;
        }
#pragma unroll
        for (int mi = 0; mi < 4; mi++)
#pragma unroll
            for (int nv = 0; nv < 2; nv++)
                o[mi][nv] = __builtin_amdgcn_mfma_f32_16x16x32_bf16(
                    pf[mi], vf[nv], o[mi][nv], 0, 0, 0);
    }

#pragma unroll
    for (int mi = 0; mi < 4; mi++) {
#pragma unroll
        for (int r = 0; r < 4; r++) {
            int i = mi * 16 + quad * 4 + r;
            if (i < TT) {
                int hh = qy * WSZ + i / WSZ, ww = qx * WSZ + i % WSZ;
                size_t orow = (size_t)b_ * NN + hh * W_ + ww;
                float inv = 1.f / rsum[mi][r];
#pragma unroll
                for (int nv = 0; nv < 2; nv++) {
                    float val = o[mi][nv][r] * inv;
                    if constexpr (YBF)
                        ybf[orow * C_ + h * 32 + nv * 16 + lr] = f2bf(val);
                    else
                        out[orow * C_ + h * 32 + nv * 16 + lr] = val;
                }
            }
        }
    }
}

// ---------------------------------------------------------------------------
// KBC: fused LIM + projection. One block = 16 positions.
// Phase 1 (= proven kb v2 body): z = bf16(bf2f(ybf) + bias + conv3x3(v)),
//   one thread = 8 channels of one position, w72 hoisted to regs, written to
//   a 16x140 LDS tile (stride 140 breaks bank aliasing on the MFMA reads).
// Phase 2: out[16x128] = z @ w_proj^T + b_proj. M=16,N=128,K=128; wave owns
//   32 cols; A frags from LDS, B frags from 32 KB L2-resident wpbf;
//   8 MFMA/wave. z NEVER touches global: saves 102.8 MB of HBM round-trip
//   and one launch vs the round-7 kb+kc pair.
// Rounding path identical to round-7 (bf16 z, then MFMA) -> absmax unchanged.
// ---------------------------------------------------------------------------
__global__ __launch_bounds__(256) void kbc_fused(
    const u16* __restrict__ v, const float* __restrict__ wlim,
    const float* __restrict__ blim, const u16* __restrict__ ybf,
    const u16* __restrict__ wpbf, const float* __restrict__ bproj,
    float* __restrict__ out)
{
    __shared__ u16 As[16][140];
    const int t   = threadIdx.x;
    const int p0  = blockIdx.x * 16;
    const int pr  = t >> 4;                    // position row 0..15
    const int c0  = (t & 15) * 8;              // channel group
    const int pos = p0 + pr;
    const int b_  = pos / NN;
    const int rem = pos - b_ * NN;
    const int hh  = rem / W_;
    const int ww  = rem - hh * W_;

    // issue the y load early (hides under weight loads + taps)
    bf16x8 yv = *(const bf16x8*)&ybf[(size_t)pos * C_ + c0];

    float w72[72];
    {
        const float* wp = &wlim[c0 * 9];
#pragma unroll
        for (int i = 0; i < 18; i++) {
            float4 f = *(const float4*)&wp[i * 4];
            w72[i * 4 + 0] = f.x; w72[i * 4 + 1] = f.y;
            w72[i * 4 + 2] = f.z; w72[i * 4 + 3] = f.w;
        }
    }
    float acc8[8];
    {
        float4 b0 = *(const float4*)&blim[c0];
        float4 b1 = *(const float4*)&blim[c0 + 4];
        acc8[0] = b0.x; acc8[1] = b0.y; acc8[2] = b0.z; acc8[3] = b0.w;
        acc8[4] = b1.x; acc8[5] = b1.y; acc8[6] = b1.z; acc8[7] = b1.w;
    }

    const u16* vbase = &v[(size_t)b_ * NN * C_ + c0];
#pragma unroll
    for (int dy = -1; dy <= 1; dy++) {
        int yy = hh + dy;
        bool yok = (unsigned)yy < (unsigned)H_;
#pragma unroll
        for (int dx = -1; dx <= 1; dx++) {
            int x2 = ww + dx;
            bool ok = yok && ((unsigned)x2 < (unsigned)W_);
            bf16x8 vv = {0, 0, 0, 0, 0, 0, 0, 0};
            if (ok) vv = *(const bf16x8*)&vbase[(size_t)(yy * W_ + x2) * C_];
            const int tap = (dy + 1) * 3 + (dx + 1);
#pragma unroll
            for (int j = 0; j < 8; j++)
                acc8[j] += bf2f((u16)vv[j]) * w72[j * 9 + tap];
        }
    }

    bf16x8 zz;
#pragma unroll
    for (int j = 0; j < 8; j++)
        zz[j] = (short)f2bf(bf2f((u16)yv[j]) + acc8[j]);
    *(bf16x8*)&As[pr][c0] = zz;
    __syncthreads();

    // ---- phase 2: tiny GEMM, wave owns 32 output cols ----
    const int wave = t >> 6, lane = t & 63, lr = lane & 15, quad = lane >> 4;
    const int wn = wave * 32;

    f32x4 acc[2];
    acc[0] = {0.f, 0.f, 0.f, 0.f};
    acc[1] = {0.f, 0.f, 0.f, 0.f};
#pragma unroll
    for (int kk = 0; kk < 4; kk++) {
        bf16x8 a = *(const bf16x8*)&As[lr][kk * 32 + quad * 8];
#pragma unroll
        for (int nj = 0; nj < 2; nj++) {
            bf16x8 b = *(const bf16x8*)&wpbf[(size_t)(wn + nj * 16 + lr) * C_ +
                                             kk * 32 + quad * 8];
            acc[nj] = __builtin_amdgcn_mfma_f32_16x16x32_bf16(a, b, acc[nj], 0, 0, 0);
        }
    }

#pragma unroll
    for (int r = 0; r < 4; r++) {
        int prow = quad * 4 + r;
#pragma unroll
        for (int nj = 0; nj < 2; nj++) {
            int c = wn + nj * 16 + lr;
            out[(size_t)(p0 + prow) * C_ + c] = acc[nj][r] + bproj[c];
        }
    }
}

// ---------------------------------------------------------------------------
// KB legacy (fallback): depthwise conv, f32 RMW into out (round-3-proven).
// ---------------------------------------------------------------------------
__global__ __launch_bounds__(256) void kb_lim(
    const u16* __restrict__ v, const float* __restrict__ wlim,
    const float* __restrict__ blim, float* __restrict__ out)
{
    const int t   = threadIdx.x;
    const int pos = blockIdx.x * 16 + (t >> 4);
    const int c0  = (t & 15) * 8;
    const int b_  = pos / NN;
    const int rem = pos - b_ * NN;
    const int hh  = rem / W_;
    const int ww  = rem - hh * W_;

    float w72[72];
    {
        const float* wp = &wlim[c0 * 9];
#pragma unroll
        for (int i = 0; i < 18; i++) {
            float4 f = *(const float4*)&wp[i * 4];
            w72[i * 4 + 0] = f.x; w72[i * 4 + 1] = f.y;
            w72[i * 4 + 2] = f.z; w72[i * 4 + 3] = f.w;
        }
    }
    float acc[8];
    {
        float4 b0 = *(const float4*)&blim[c0];
        float4 b1 = *(const float4*)&blim[c0 + 4];
        acc[0] = b0.x; acc[1] = b0.y; acc[2] = b0.z; acc[3] = b0.w;
        acc[4] = b1.x; acc[5] = b1.y; acc[6] = b1.z; acc[7] = b1.w;
    }

    const u16* vbase = &v[(size_t)b_ * NN * C_ + c0];
#pragma unroll
    for (int dy = -1; dy <= 1; dy++) {
        int yy = hh + dy;
        bool yok = (unsigned)yy < (unsigned)H_;
#pragma unroll
        for (int dx = -1; dx <= 1; dx++) {
            int x2 = ww + dx;
            bool ok = yok && ((unsigned)x2 < (unsigned)W_);
            bf16x8 vv = {0, 0, 0, 0, 0, 0, 0, 0};
            if (ok) vv = *(const bf16x8*)&vbase[(size_t)(yy * W_ + x2) * C_];
            const int tap = (dy + 1) * 3 + (dx + 1);
#pragma unroll
            for (int j = 0; j < 8; j++)
                acc[j] += bf2f((u16)vv[j]) * w72[j * 9 + tap];
        }
    }

    float* op = &out[(size_t)pos * C_ + c0];
    float4 o0 = *(const float4*)&op[0];
    float4 o1 = *(const float4*)&op[4];
    o0.x += acc[0]; o0.y += acc[1]; o0.z += acc[2]; o0.w += acc[3];
    o1.x += acc[4]; o1.y += acc[5]; o1.z += acc[6]; o1.w += acc[7];
    *(float4*)&op[0] = o0;
    *(float4*)&op[4] = o1;
}

// ---------------------------------------------------------------------------
// KC legacy (fallback): staged gemm_bt. MODE 1: A from f32 y + f2bf, W from
// wpbf. MODE 0: full f32.
// ---------------------------------------------------------------------------
template <int MODE>
__global__ __launch_bounds__(256) void kc_proj(
    float* __restrict__ y, const float* __restrict__ wproj,
    const u16* __restrict__ wpbf, const float* __restrict__ bproj)
{
    __shared__ u16 As[128][72];
    __shared__ u16 Ws[128][72];
    const int t    = threadIdx.x;
    const int m0   = blockIdx.x * 128;
    const int wave = t >> 6, lane = t & 63, lr = lane & 15, quad = lane >> 4;
    const int wm = (wave >> 1) * 64, wn = (wave & 1) * 64;

    f32x4 acc[4][4];
#pragma unroll
    for (int mi = 0; mi < 4; mi++)
#pragma unroll
        for (int ni = 0; ni < 4; ni++) acc[mi][ni] = {0.f, 0.f, 0.f, 0.f};

#pragma unroll
    for (int kt = 0; kt < 2; kt++) {
        const int k0 = kt * 64;
#pragma unroll
        for (int p = 0; p < 8; p++) {
            int e   = p * 256 + t;
            int row = e >> 4;
            int col = (e & 15) * 4;
            float4 fa = *(const float4*)&y[(size_t)(m0 + row) * C_ + k0 + col];
            ushort4 ua;
            ua.x = f2bf(fa.x); ua.y = f2bf(fa.y);
            ua.z = f2bf(fa.z); ua.w = f2bf(fa.w);
            *(ushort4*)&As[row][col] = ua;
            if constexpr (MODE == 0) {
                float4 fw = *(const float4*)&wproj[(size_t)row * C_ + k0 + col];
                ushort4 uw;
                uw.x = f2bf(fw.x); uw.y = f2bf(fw.y);
                uw.z = f2bf(fw.z); uw.w = f2bf(fw.w);
                *(ushort4*)&Ws[row][col] = uw;
            }
        }
        if constexpr (MODE >= 1) {
#pragma unroll
            for (int p4 = 0; p4 < 4; p4++) {
                int e    = p4 * 256 + t;
                int row  = e >> 3;
                int col8 = (e & 7) * 8;
                *(bf16x8*)&Ws[row][col8] =
                    *(const bf16x8*)&wpbf[(size_t)row * C_ + k0 + col8];
            }
        }
        __syncthreads();
#pragma unroll
        for (int kk = 0; kk < 2; kk++) {
            bf16x8 a[4], b[4];
#pragma unroll
            for (int mi = 0; mi < 4; mi++)
                a[mi] = *(const bf16x8*)&As[wm + mi * 16 + lr][kk * 32 + quad * 8];
#pragma unroll
            for (int ni = 0; ni < 4; ni++)
                b[ni] = *(const bf16x8*)&Ws[wn + ni * 16 + lr][kk * 32 + quad * 8];
#pragma unroll
            for (int mi = 0; mi < 4; mi++)
#pragma unroll
                for (int ni = 0; ni < 4; ni++)
                    acc[mi][ni] = __builtin_amdgcn_mfma_f32_16x16x32_bf16(
                        a[mi], b[ni], acc[mi][ni], 0, 0, 0);
        }
        if (kt == 0) __syncthreads();
    }

#pragma unroll
    for (int mi = 0; mi < 4; mi++) {
#pragma unroll
        for (int r = 0; r < 4; r++) {
            int m = m0 + wm + mi * 16 + quad * 4 + r;
#pragma unroll
            for (int ni = 0; ni < 4; ni++) {
                int c = wn + ni * 16 + lr;
                y[(size_t)m * C_ + c] = acc[mi][ni][r] + bproj[c];
            }
        }
    }
}

extern "C" void kernel_launch(void* const* d_in, const int* in_sizes, int n_in,
                              void* d_out, int out_size, void* d_ws, size_t ws_size,
                              hipStream_t stream)
{
    const float* x     = (const float*)d_in[0];
    const float* wqkv  = (const float*)d_in[1];
    const float* wlim  = (const float*)d_in[2];
    const float* blim  = (const float*)d_in[3];
    const float* wproj = (const float*)d_in[4];
    const float* bproj = (const float*)d_in[5];
    float* out = (float*)d_out;
    u16*   v   = (u16*)d_ws;                         // 51,380,224 B bf16 image v

    const size_t vbytes = (size_t)MM * C_ * 2;       // 51,380,224 (256B-aligned)
    const size_t wbytes = (49152 + 16384) * 2;       // 131,072
    const size_t need1  = vbytes + wbytes;           // weights path
    const size_t need2  = need1 + vbytes;            // + bf16 ybf buffer

    if (ws_size >= need2) {
        u16* wqbf = (u16*)((char*)d_ws + vbytes);
        u16* wpbf = wqbf + 49152;
        u16* ybf  = (u16*)((char*)d_ws + need1);
        kw_cvt<<<dim3(64), 256, 0, stream>>>(wqkv, wproj, wqbf, wpbf);
        ka_fused<true, true><<<dim3(B_ * 64), 256, 0, stream>>>(
            x, wqkv, wqbf, v, ybf, nullptr);
        kbc_fused<<<dim3(MM / 16), 256, 0, stream>>>(
            v, wlim, blim, ybf, wpbf, bproj, out);
    } else if (ws_size >= need1) {
        u16* wqbf = (u16*)((char*)d_ws + vbytes);
        u16* wpbf = wqbf + 49152;
        kw_cvt<<<dim3(64), 256, 0, stream>>>(wqkv, wproj, wqbf, wpbf);
        ka_fused<true, false><<<dim3(B_ * 64), 256, 0, stream>>>(
            x, wqkv, wqbf, v, nullptr, out);
        kb_lim<<<dim3(MM / 16), 256, 0, stream>>>(v, wlim, blim, out);
        kc_proj<1><<<dim3(MM / 128), 256, 0, stream>>>(out, nullptr, wpbf, bproj);
    } else {
        ka_fused<false, false><<<dim3(B_ * 64), 256, 0, stream>>>(
            x, wqkv, nullptr, v, nullptr, out);
        kb_lim<<<dim3(MM / 16), 256, 0, stream>>>(v, wlim, blim, out);
        kc_proj<0><<<dim3(MM / 128), 256, 0, stream>>>(out, wproj, nullptr, bproj);
    }
}